// Round 4
// baseline (1261.518 us; speedup 1.0000x reference)
//
#include <hip/hip_runtime.h>
#include <hip/hip_bf16.h>

// ---------------------------------------------------------------------------
// Fused triplane-sample + 3-layer MLP (3 resolution levels), bf16 MFMA.
//
//  - prologue kernel packs W1/W2/W3 (fp32) -> bf16 in exact
//    mfma_f32_16x16x32_bf16 B-fragment order into d_ws (L2-resident, ~400KB),
//    pads K/N dims with zeros, and pre-sums the three b3 biases.
//  - main kernel: 64 points per block, 256 threads (4 waves).
//    level loop: sample 3 planes (192 threads, float4 taps) -> bf16 feats in
//    LDS -> L1 -> relu -> LDS -> L2 -> relu -> LDS -> L3 accumulated in
//    registers across levels. Weights fetched directly global->VGPR
//    (pre-swizzled fragments, L2 hot) - no W staging in LDS.
//  - biases folded into MFMA accumulator init; B-fragments for layer k+1
//    issued during layer k's epilogue so L2 latency hides under stores.
//  - LDS strides: odd multiples of 8 shorts (16B row alignment for b128
//    reads; per-16-lane start banks cover 32 banks 2x -> free per m136).
//    H_LD=200 (100 dw), sFeat stride 104 (52 dw).
//  - MFMA fragments typed as ext_vector(8) short (guide-verified signature).
// ---------------------------------------------------------------------------

typedef short frag8 __attribute__((ext_vector_type(8)));
typedef float f32x4 __attribute__((ext_vector_type(4)));

static __device__ __forceinline__ short f2bf(float f) {
    return __builtin_bit_cast(short, (__bf16)f);
}

#define LVL_STRIDE (132 * 1024)          // bytes of packed frags per level
#define W2_OFF (36 * 1024)               // within a level
#define W3_OFF (108 * 1024)
#define B1P_OFF (396 * 1024)             // fp32 [3][192]
#define B2P_OFF (B1P_OFF + 2304)         // fp32 [3][192]
#define B3S_OFF (B2P_OFF + 2304)         // fp32 [64] summed over levels

#define H_LD 200                          // sH1/sH2 leading dim (shorts)

struct PlanesArg { const float* p[9]; };

// -------------------------- weight pack kernel -----------------------------
__global__ void pack_weights(const float* __restrict__ W1g, const float* __restrict__ b1g,
                             const float* __restrict__ W2g, const float* __restrict__ b2g,
                             const float* __restrict__ W3g, const float* __restrict__ b3g,
                             char* __restrict__ ws)
{
    int gid = blockIdx.x * 256 + threadIdx.x;
    int fid = gid >> 6;
    int lane = gid & 63;
    if (fid < 396) {
        // fragment fid -> (level, layer, n-tile, k-step); 1KB per fragment.
        // B-fragment: lane holds B[k = 8*(lane>>4)+j][col = ntile*16 + (lane&15)]
        int lvl = fid / 132;
        int r = fid - lvl * 132;
        int l15 = lane & 15;
        int kg = (lane >> 4) << 3;
        frag8 vals;
        if (r < 36) {                       // layer 1: W1 [72][168], K padded per-plane 24->32
            int n = r / 3, s = r - n * 3;   // n: 0..11 (N=192), s: 0..2 (K=96)
            int col = n * 16 + l15;
            const float* Wp = W1g + lvl * 72 * 168;
            #pragma unroll
            for (int j = 0; j < 8; ++j) {
                int f = kg + j;             // feature within plane block (plane = s)
                float v = 0.f;
                if (f < 24 && col < 168) v = Wp[(s * 24 + f) * 168 + col];
                vals[j] = f2bf(v);
            }
        } else if (r < 108) {               // layer 2: W2 [168][168], K pad ->192
            int rr = r - 36;
            int n = rr / 6, s = rr - n * 6; // n: 0..11, s: 0..5
            int col = n * 16 + l15;
            const float* Wp = W2g + lvl * 168 * 168;
            #pragma unroll
            for (int j = 0; j < 8; ++j) {
                int k = s * 32 + kg + j;
                float v = 0.f;
                if (k < 168 && col < 168) v = Wp[k * 168 + col];
                vals[j] = f2bf(v);
            }
        } else {                            // layer 3: W3 [168][53], N pad ->64
            int rr = r - 108;
            int n = rr / 6, s = rr - n * 6; // n: 0..3, s: 0..5
            int col = n * 16 + l15;
            const float* Wp = W3g + lvl * 168 * 53;
            #pragma unroll
            for (int j = 0; j < 8; ++j) {
                int k = s * 32 + kg + j;
                float v = 0.f;
                if (k < 168 && col < 53) v = Wp[k * 53 + col];
                vals[j] = f2bf(v);
            }
        }
        *(frag8*)(ws + (size_t)fid * 1024 + lane * 16) = vals;
    } else {
        int bid = gid - 396 * 64;
        float* b1p = (float*)(ws + B1P_OFF);
        float* b2p = (float*)(ws + B2P_OFF);
        float* b3s = (float*)(ws + B3S_OFF);
        if (bid < 576) {
            int lvl = bid / 192, c = bid - lvl * 192;
            b1p[bid] = (c < 168) ? b1g[lvl * 168 + c] : 0.f;
        } else if (bid < 1152) {
            int t = bid - 576;
            int lvl = t / 192, c = t - lvl * 192;
            b2p[t] = (c < 168) ? b2g[lvl * 168 + c] : 0.f;
        } else if (bid < 1216) {
            int c = bid - 1152;
            b3s[c] = (c < 53) ? (b3g[c] + b3g[53 + c] + b3g[106 + c]) : 0.f;
        }
    }
}

// ------------------------------ main kernel --------------------------------
__global__ __launch_bounds__(256, 2)
void fused_triplane_mlp(const float* __restrict__ x, PlanesArg pl,
                        const char* __restrict__ ws, float* __restrict__ out, int N)
{
    __shared__ __align__(16) short sFeat[64][104];   // K=96 used (3 planes x 32)
    __shared__ __align__(16) short sH1[64][H_LD];    // K=192 used
    __shared__ __align__(16) short sH2[64][H_LD];
    __shared__ float sX[192];

    const int tid = threadIdx.x;
    const int lane = tid & 63;
    const int w = tid >> 6;        // wave id 0..3
    const int l15 = lane & 15;
    const int g = lane >> 4;       // k-group 0..3
    const int blk = blockIdx.x;

    if (tid < 192) {
        int gi = blk * 192 + tid;
        sX[tid] = (gi < N * 3) ? x[gi] : 0.f;
    }
    __syncthreads();

    const float* b1p = (const float*)(ws + B1P_OFF);
    const float* b2p = (const float*)(ws + B2P_OFF);
    const float* b3s = (const float*)(ws + B3S_OFF);

    const int col = w * 16 + l15;  // this lane's output column (all layers)

    // out accumulator across levels, initialized with summed b3 (pad cols = 0)
    f32x4 outAcc[4];
    {
        float b3v = b3s[col];
        #pragma unroll
        for (int m = 0; m < 4; ++m)
            #pragma unroll
            for (int e = 0; e < 4; ++e) outAcc[m][e] = b3v;
    }

    const int p = tid & 63;   // sampler point (tid<192)
    const int q = tid >> 6;   // sampler plane 0..2

    for (int lvl = 0; lvl < 3; ++lvl) {
        const char* wbase = ws + lvl * LVL_STRIDE;

        // ---- triplane bilinear sampling: (plane q, point p) per thread ----
        if (tid < 192) {
            const int S = 64 << lvl;
            float xu = sX[p * 3 + 0], xv = sX[p * 3 + 1], xw = sX[p * 3 + 2];
            float a = (q == 2) ? xv : xu;
            float b = (q == 0) ? xv : xw;
            a = fminf(fmaxf(a, 0.f), 1.f) * (float)(S - 1);
            b = fminf(fmaxf(b, 0.f), 1.f) * (float)(S - 1);
            int i0 = (int)a; i0 = (i0 < S - 2) ? i0 : (S - 2);
            int j0 = (int)b; j0 = (j0 < S - 2) ? j0 : (S - 2);
            float wa = a - (float)i0;
            float wb = b - (float)j0;
            const float* P0 = pl.p[lvl * 3 + q] + (size_t)(i0 * S + j0) * 24;
            const float* P1 = P0 + (size_t)S * 24;
            #pragma unroll
            for (int c = 0; c < 3; ++c) {
                f32x4 v00a = *(const f32x4*)(P0 + c * 8);
                f32x4 v00b = *(const f32x4*)(P0 + c * 8 + 4);
                f32x4 v01a = *(const f32x4*)(P0 + 24 + c * 8);
                f32x4 v01b = *(const f32x4*)(P0 + 24 + c * 8 + 4);
                f32x4 v10a = *(const f32x4*)(P1 + c * 8);
                f32x4 v10b = *(const f32x4*)(P1 + c * 8 + 4);
                f32x4 v11a = *(const f32x4*)(P1 + 24 + c * 8);
                f32x4 v11b = *(const f32x4*)(P1 + 24 + c * 8 + 4);
                frag8 ov;
                #pragma unroll
                for (int e = 0; e < 4; ++e) {
                    float t0 = v00a[e] + wa * (v10a[e] - v00a[e]);
                    float t1 = v01a[e] + wa * (v11a[e] - v01a[e]);
                    ov[e] = f2bf(t0 + wb * (t1 - t0));
                    float u0 = v00b[e] + wa * (v10b[e] - v00b[e]);
                    float u1 = v01b[e] + wa * (v11b[e] - v01b[e]);
                    ov[4 + e] = f2bf(u0 + wb * (u1 - u0));
                }
                *(frag8*)(&sFeat[p][q * 32 + c * 8]) = ov;
            }
            frag8 z = (frag8)0;
            *(frag8*)(&sFeat[p][q * 32 + 24]) = z;   // zero K-pad 24..31
        }

        // ---- preload layer-1 B fragments + bias (overlaps sampling) ----
        frag8 B1[3][3];
        float bias1[3];
        #pragma unroll
        for (int n = 0; n < 3; ++n) {
            bias1[n] = b1p[lvl * 192 + (3 * w + n) * 16 + l15];
            #pragma unroll
            for (int s = 0; s < 3; ++s)
                B1[n][s] = *(const frag8*)(wbase + (size_t)((3 * w + n) * 3 + s) * 1024 + lane * 16);
        }
        __syncthreads();

        // ---- layer 1: [64x96] @ [96x192] ----
        frag8 B2[3][6];
        float bias2[3];
        {
            f32x4 acc[4][3];
            #pragma unroll
            for (int m = 0; m < 4; ++m)
                #pragma unroll
                for (int n = 0; n < 3; ++n)
                    #pragma unroll
                    for (int e = 0; e < 4; ++e) acc[m][n][e] = bias1[n];
            #pragma unroll
            for (int m = 0; m < 4; ++m) {
                frag8 A[3];
                #pragma unroll
                for (int s = 0; s < 3; ++s)
                    A[s] = *(const frag8*)(&sFeat[m * 16 + l15][s * 32 + g * 8]);
                #pragma unroll
                for (int n = 0; n < 3; ++n)
                    #pragma unroll
                    for (int s = 0; s < 3; ++s)
                        acc[m][n] = __builtin_amdgcn_mfma_f32_16x16x32_bf16(A[s], B1[n][s], acc[m][n], 0, 0, 0);
            }
            // issue layer-2 fragment loads now: latency hides under epilogue+barrier
            #pragma unroll
            for (int n = 0; n < 3; ++n) {
                bias2[n] = b2p[lvl * 192 + (3 * w + n) * 16 + l15];
                #pragma unroll
                for (int s = 0; s < 6; ++s)
                    B2[n][s] = *(const frag8*)(wbase + W2_OFF + (size_t)((3 * w + n) * 6 + s) * 1024 + lane * 16);
            }
            #pragma unroll
            for (int m = 0; m < 4; ++m)
                #pragma unroll
                for (int n = 0; n < 3; ++n)
                    #pragma unroll
                    for (int r = 0; r < 4; ++r) {
                        float h = fmaxf(acc[m][n][r], 0.f);
                        sH1[m * 16 + g * 4 + r][(3 * w + n) * 16 + l15] = f2bf(h);
                    }
        }
        __syncthreads();

        // ---- layer 2: [64x192] @ [192x192] ----
        frag8 B3[6];
        {
            f32x4 acc[4][3];
            #pragma unroll
            for (int m = 0; m < 4; ++m)
                #pragma unroll
                for (int n = 0; n < 3; ++n)
                    #pragma unroll
                    for (int e = 0; e < 4; ++e) acc[m][n][e] = bias2[n];
            #pragma unroll
            for (int m = 0; m < 4; ++m) {
                frag8 A[6];
                #pragma unroll
                for (int s = 0; s < 6; ++s)
                    A[s] = *(const frag8*)(&sH1[m * 16 + l15][s * 32 + g * 8]);
                #pragma unroll
                for (int n = 0; n < 3; ++n)
                    #pragma unroll
                    for (int s = 0; s < 6; ++s)
                        acc[m][n] = __builtin_amdgcn_mfma_f32_16x16x32_bf16(A[s], B2[n][s], acc[m][n], 0, 0, 0);
            }
            // issue layer-3 fragment loads now
            #pragma unroll
            for (int s = 0; s < 6; ++s)
                B3[s] = *(const frag8*)(wbase + W3_OFF + (size_t)(w * 6 + s) * 1024 + lane * 16);
            #pragma unroll
            for (int m = 0; m < 4; ++m)
                #pragma unroll
                for (int n = 0; n < 3; ++n)
                    #pragma unroll
                    for (int r = 0; r < 4; ++r) {
                        float h = fmaxf(acc[m][n][r], 0.f);
                        sH2[m * 16 + g * 4 + r][(3 * w + n) * 16 + l15] = f2bf(h);
                    }
        }
        __syncthreads();

        // ---- layer 3: [64x192] @ [192x64], accumulate across levels ----
        {
            #pragma unroll
            for (int m = 0; m < 4; ++m) {
                frag8 A[6];
                #pragma unroll
                for (int s = 0; s < 6; ++s)
                    A[s] = *(const frag8*)(&sH2[m * 16 + l15][s * 32 + g * 8]);
                #pragma unroll
                for (int s = 0; s < 6; ++s)
                    outAcc[m] = __builtin_amdgcn_mfma_f32_16x16x32_bf16(A[s], B3[s], outAcc[m], 0, 0, 0);
            }
        }
        // no barrier needed: next-level LDS writes are separated from this
        // level's reads by >=1 __syncthreads() (hazard analysis in journal).
    }

    // ---- epilogue: out[row][col] (b3 already folded into outAcc init) ----
    if (col < 53) {
        #pragma unroll
        for (int m = 0; m < 4; ++m)
            #pragma unroll
            for (int r = 0; r < 4; ++r) {
                int row = blk * 64 + m * 16 + g * 4 + r;
                if (row < N) out[(size_t)row * 53 + col] = outAcc[m][r];
            }
    }
}

// ------------------------------ launcher -----------------------------------
extern "C" void kernel_launch(void* const* d_in, const int* in_sizes, int n_in,
                              void* d_out, int out_size, void* d_ws, size_t ws_size,
                              hipStream_t stream)
{
    const float* x = (const float*)d_in[0];
    PlanesArg pl;
    for (int k = 0; k < 9; ++k) pl.p[k] = (const float*)d_in[1 + k];
    const float* W1 = (const float*)d_in[10];
    const float* b1 = (const float*)d_in[11];
    const float* W2 = (const float*)d_in[12];
    const float* b2 = (const float*)d_in[13];
    const float* W3 = (const float*)d_in[14];
    const float* b3 = (const float*)d_in[15];

    char* ws = (char*)d_ws;
    const int N = in_sizes[0] / 3;

    // 396 fragments * 64 lanes + 1216 bias elements = 26560 threads
    pack_weights<<<104, 256, 0, stream>>>(W1, b1, W2, b2, W3, b3, ws);

    int nblk = (N + 63) / 64;
    fused_triplane_mlp<<<nblk, 256, 0, stream>>>(x, pl, ws, (float*)d_out, N);
}